// Round 4
// baseline (12446.000 us; speedup 1.0000x reference)
//
#include <hip/hip_runtime.h>

#define BATCH 8
#define N 32768
#define NPOINT 2048
#define NT 512               // threads per block (8 waves)
#define NW 8                 // waves per block
#define NCELL 1024           // Morton cells: 16 x 8 x 8
#define SENT 0x7fffffff

typedef __attribute__((ext_vector_type(2))) float f2;

// One block per batch.  One-time spatial counting-sort (Morton cells) into
// d_ws so each wave owns 4096 spatially-compact points; per iteration a wave
// whose bbox lower-bound distance to the pivot >= its cached max-temp skips
// the whole update (provably a bit-exact no-op in float arithmetic: the
// bound uses the SAME rounded subtract/square expressions, and fl is
// monotone).  Structure otherwise identical to the proven round-0 kernel:
// x,y,temp in registers (AGPR-backed), z in LDS, 2 barriers/iter.
// Bit-exact numpy semantics: contract off, (xx+yy)+zz order, lowest ORIGINAL
// index on ties (orig idx fetched from ws during winner-only rescan).

#define REP32(M)  M(0)  M(1)  M(2)  M(3)  M(4)  M(5)  M(6)  M(7)  \
                  M(8)  M(9)  M(10) M(11) M(12) M(13) M(14) M(15) \
                  M(16) M(17) M(18) M(19) M(20) M(21) M(22) M(23) \
                  M(24) M(25) M(26) M(27) M(28) M(29) M(30) M(31)

__global__ __attribute__((amdgpu_flat_work_group_size(NT, NT),
                          amdgpu_waves_per_eu(2, 2)))
void fps_kernel(const float* __restrict__ pts_t,  // (B,3,N)
                float* __restrict__ out,          // (B,3,NPOINT)
                float* __restrict__ ws)           // >= B*4*N floats
{
#pragma clang fp contract(off)
    __shared__ f2       s_z[N / 2];      // 128 KiB (sorted-order z)
    __shared__ unsigned s_M[NPOINT];     // 8 KiB: per-iter max (float bits)
    __shared__ int      s_besti[NPOINT]; // 8 KiB: per-iter argmin orig idx
    __shared__ float    s_red[48];       // 6 x 8 wave partials (setup only)

    const int b = blockIdx.x;
    const int t = threadIdx.x;
    const int w = t >> 6;                // wave id
    const int l = t & 63;                // lane id

    const float* __restrict__ px = pts_t + (size_t)b * 3 * N;
    const float* __restrict__ py = px + N;
    const float* __restrict__ pz = py + N;
    float* outx = out + (size_t)b * 3 * NPOINT;
    float* outy = outx + NPOINT;
    float* outz = outy + NPOINT;

    float* wsx = ws + (size_t)b * 4 * N;
    float* wsy = wsx + N;
    float* wsz = wsy + N;
    int*   wsi = (int*)(wsz + N);

    // ================= SETUP: axis ranges =================
    float axlo = 1e30f, axhi = -1e30f, aylo = 1e30f, ayhi = -1e30f,
          azlo = 1e30f, azhi = -1e30f;
    for (int k = 0; k < 64; ++k) {
        const int i = k * NT + t;
        const float x = px[i], y = py[i], z = pz[i];
        axlo = fminf(axlo, x); axhi = fmaxf(axhi, x);
        aylo = fminf(aylo, y); ayhi = fmaxf(ayhi, y);
        azlo = fminf(azlo, z); azhi = fmaxf(azhi, z);
    }
#pragma unroll
    for (int off = 32; off >= 1; off >>= 1) {
        axlo = fminf(axlo, __shfl_xor(axlo, off)); axhi = fmaxf(axhi, __shfl_xor(axhi, off));
        aylo = fminf(aylo, __shfl_xor(aylo, off)); ayhi = fmaxf(ayhi, __shfl_xor(ayhi, off));
        azlo = fminf(azlo, __shfl_xor(azlo, off)); azhi = fmaxf(azhi, __shfl_xor(azhi, off));
    }
    if (l == 0) {
        s_red[w]      = axlo; s_red[8 + w]  = axhi;
        s_red[16 + w] = aylo; s_red[24 + w] = ayhi;
        s_red[32 + w] = azlo; s_red[40 + w] = azhi;
    }
    for (int i = t; i < NCELL; i += NT) s_M[i] = 0u;   // zero histogram
    __syncthreads();
    axlo = s_red[0];  axhi = s_red[8];
    aylo = s_red[16]; ayhi = s_red[24];
    azlo = s_red[32]; azhi = s_red[40];
    for (int i = 1; i < NW; ++i) {
        axlo = fminf(axlo, s_red[i]);      axhi = fmaxf(axhi, s_red[8 + i]);
        aylo = fminf(aylo, s_red[16 + i]); ayhi = fmaxf(ayhi, s_red[24 + i]);
        azlo = fminf(azlo, s_red[32 + i]); azhi = fmaxf(azhi, s_red[40 + i]);
    }
    const float sx = 16.0f / (axhi - axlo + 1e-20f);
    const float sy =  8.0f / (ayhi - aylo + 1e-20f);
    const float sz =  8.0f / (azhi - azlo + 1e-20f);

    // Morton-ish cell id: x 4 bits, y 3 bits, z 3 bits, interleaved
    auto cellof = [&](float x, float y, float z) -> int {
        int ux = (int)((x - axlo) * sx); ux = ux < 0 ? 0 : (ux > 15 ? 15 : ux);
        int uy = (int)((y - aylo) * sy); uy = uy < 0 ? 0 : (uy > 7 ? 7 : uy);
        int uz = (int)((z - azlo) * sz); uz = uz < 0 ? 0 : (uz > 7 ? 7 : uz);
        return ((ux >> 3 & 1) << 9) | ((uy >> 2 & 1) << 8) | ((uz >> 2 & 1) << 7)
             | ((ux >> 2 & 1) << 6) | ((uy >> 1 & 1) << 5) | ((uz >> 1 & 1) << 4)
             | ((ux >> 1 & 1) << 3) | ((uy & 1) << 2)      | ((uz & 1) << 1)
             | (ux & 1);
    };

    // ---- histogram ----
    for (int k = 0; k < 64; ++k) {
        const int i = k * NT + t;
        atomicAdd(&s_M[cellof(px[i], py[i], pz[i])], 1u);
    }
    __syncthreads();
    // ---- keep counts, inclusive scan s_M (Hillis-Steele), exclusive base ----
    for (int i = t; i < NCELL; i += NT) s_besti[i] = (int)s_M[i];
    __syncthreads();
    for (int s = 1; s < NCELL; s <<= 1) {
        const unsigned v0 = (t >= s) ? s_M[t - s] : 0u;
        const unsigned v1 = (t + NT >= s) ? s_M[t + NT - s] : 0u;
        __syncthreads();
        s_M[t] += v0;
        s_M[t + NT] += v1;
        __syncthreads();
    }
    for (int i = t; i < NCELL; i += NT) s_besti[i] = (int)s_M[i] - s_besti[i];
    __syncthreads();
    // ---- scatter (rank via atomicAdd on exclusive base; exact permutation) ----
    for (int k = 0; k < 64; ++k) {
        const int i = k * NT + t;
        const float x = px[i], y = py[i], z = pz[i];
        const int c = cellof(x, y, z);
        const int pos = atomicAdd(&s_besti[c], 1);
        wsx[pos] = x; wsy[pos] = y; wsz[pos] = z; wsi[pos] = i;
    }
    __syncthreads();

    // ================= owned loads: wave w owns positions [4096w,4096w+4096) =================
    const f2* wsx2 = (const f2*)wsx;
    const f2* wsy2 = (const f2*)wsy;
    const f2* wsz2 = (const f2*)wsz;
    const int2* wsi2 = (const int2*)wsi;

#define DECL(k) f2 x##k, y##k, T##k;
    REP32(DECL)
#undef DECL

    float bxlo = 1e30f, bxhi = -1e30f, bylo = 1e30f, byhi = -1e30f,
          bzlo = 1e30f, bzhi = -1e30f;
#define LOADK(k) { const int q = w * 2048 + (k) * 64 + l;            \
                   x##k = wsx2[q]; y##k = wsy2[q];                   \
                   const f2 z2 = wsz2[q]; s_z[q] = z2;               \
                   T##k = (f2){1e10f, 1e10f};                        \
                   bxlo = fminf(bxlo, fminf(x##k.x, x##k.y));        \
                   bxhi = fmaxf(bxhi, fmaxf(x##k.x, x##k.y));        \
                   bylo = fminf(bylo, fminf(y##k.x, y##k.y));        \
                   byhi = fmaxf(byhi, fmaxf(y##k.x, y##k.y));        \
                   bzlo = fminf(bzlo, fminf(z2.x, z2.y));            \
                   bzhi = fmaxf(bzhi, fmaxf(z2.x, z2.y)); }
    REP32(LOADK)
#undef LOADK
#pragma unroll
    for (int off = 32; off >= 1; off >>= 1) {
        bxlo = fminf(bxlo, __shfl_xor(bxlo, off)); bxhi = fmaxf(bxhi, __shfl_xor(bxhi, off));
        bylo = fminf(bylo, __shfl_xor(bylo, off)); byhi = fmaxf(byhi, __shfl_xor(byhi, off));
        bzlo = fminf(bzlo, __shfl_xor(bzlo, off)); bzhi = fmaxf(bzhi, __shfl_xor(bzhi, off));
    }

    // ---- re-init per-iteration slots ----
    for (int i = t; i < NPOINT; i += NT) { s_M[i] = 0u; s_besti[i] = SENT; }

    // First selected index is 0 (reference: idx[0] = 0).
    float lx = px[0], ly = py[0], lz = pz[0];
    if (t == 0) { outx[0] = lx; outy[0] = ly; outz[0] = lz; }
    __syncthreads();

    float vmax_w = 1e10f;   // wave's current max temp (lane-uniform)

    // ================= main loop =================
    for (int j = 1; j < NPOINT; ++j) {
        // exact lower bound of float d2 to any point in this wave's bbox
        const float dxw = fmaxf(0.0f, fmaxf(bxlo - lx, lx - bxhi));
        const float dyw = fmaxf(0.0f, fmaxf(bylo - ly, ly - byhi));
        const float dzw = fmaxf(0.0f, fmaxf(bzlo - lz, lz - bzhi));
        const float lb  = (dxw * dxw + dyw * dyw) + dzw * dzw;

        if (lb < vmax_w) {                 // wave-uniform: skip = exact no-op
            const f2 lx2 = (f2){lx, lx};
            const f2 ly2 = (f2){ly, ly};
            const f2 lz2 = (f2){lz, lz};
            f2 mx = (f2){0.0f, 0.0f};
#define UPD(k) { const int q = w * 2048 + (k) * 64 + l;                  \
                 f2 dz = s_z[q] - lz2;                                   \
                 f2 dx = x##k - lx2;                                     \
                 f2 dy = y##k - ly2;                                     \
                 f2 s  = (dx * dx + dy * dy) + dz * dz; /* numpy order */\
                 T##k.x = fminf(T##k.x, s.x);                            \
                 T##k.y = fminf(T##k.y, s.y);                            \
                 mx.x = fmaxf(mx.x, T##k.x);                             \
                 mx.y = fmaxf(mx.y, T##k.y); }
            REP32(UPD)
#undef UPD
            float v = fmaxf(mx.x, mx.y);
#pragma unroll
            for (int off = 32; off >= 1; off >>= 1)
                v = fmaxf(v, __shfl_xor(v, off));
            vmax_w = v;
        }

        if (l == 0) atomicMax(&s_M[j], __float_as_uint(vmax_w));
        __syncthreads();                   // barrier 1

        const float M = __uint_as_float(s_M[j]);

        // --- lazy argmax: winner wave(s) rescan; tie-break on ORIGINAL idx ---
        if (vmax_w == M) {                 // wave-uniform
            int cand = SENT;
#define SCANK(k) { const int q = w * 2048 + (k) * 64 + l;        \
                   const int2 I = wsi2[q];                       \
                   int c0 = (T##k.x == M) ? I.x : SENT;          \
                   const int c1 = (T##k.y == M) ? I.y : SENT;    \
                   c0 = c0 < c1 ? c0 : c1;                       \
                   cand = c0 < cand ? c0 : cand; }
            REP32(SCANK)
#undef SCANK
            if (cand != SENT) atomicMin(&s_besti[j], cand);
        }
        __syncthreads();                   // barrier 2

        const int sel = __builtin_amdgcn_readfirstlane(s_besti[j]);
        lx = px[sel];                      // uniform -> scalar load (L2-hit)
        ly = py[sel];
        lz = pz[sel];
        if (t == 0) { outx[j] = lx; outy[j] = ly; outz[j] = lz; }
    }
}

extern "C" void kernel_launch(void* const* d_in, const int* in_sizes, int n_in,
                              void* d_out, int out_size, void* d_ws, size_t ws_size,
                              hipStream_t stream) {
    // d_in[0]: points_xyz (B,N,3) — unused
    // d_in[1]: points_xyz_t (B,3,N)
    // d_in[2]: features_with_xyz (B,67,N) — unused
    // d_ws: used as B*4*N floats (4 MiB) for the spatially-sorted copy
    const float* pts_t = (const float*)d_in[1];
    float* out = (float*)d_out;
    fps_kernel<<<BATCH, NT, 0, stream>>>(pts_t, out, (float*)d_ws);
}

// Round 5
// 5296.038 us; speedup vs baseline: 2.3501x; 2.3501x over previous
//
#include <hip/hip_runtime.h>

#define BATCH 8
#define KSPLIT 4                       // blocks (CUs) per batch
#define NBLK (BATCH * KSPLIT)          // 32 blocks, all co-resident
#define N 32768
#define NPOINT 2048
#define NT 512                         // threads per block (8 waves)
#define QB (N / 2 / KSPLIT)            // f2 elems per block = 4096
#define SENTK 0xffffffffffffffffull

typedef __attribute__((ext_vector_type(2))) float f2;

// Multi-CU FPS: each batch is split across KSPLIT blocks (swizzled so all
// land on ONE XCD: blkid = k*8 + b under round-robin dispatch -> shared L2).
// All point state (x,y,z,temp) in registers: 16 pts/thread = 8 f2 per array.
// Per iteration: block-local UPD + wave reduce + packed u64 LDS key ->
// one device-scope atomicMax into gkey[b][j] + arrive counter + RMW spin.
// Key = (dist_bits<<32 | N-idx): max dist, lowest original index on ties
// (dist >= 0 so float bits are monotone) -- the scheme that passed round 2.
// Bit-exact numpy semantics: contract off, (xx+yy)+zz order, no FMA.

#define REP8(M)  M(0) M(1) M(2) M(3) M(4) M(5) M(6) M(7)
#define REP8R(M) M(7) M(6) M(5) M(4) M(3) M(2) M(1) M(0)

__global__ __attribute__((amdgpu_flat_work_group_size(NT, NT),
                          amdgpu_waves_per_eu(2, 2)))
void fps_kernel(const float* __restrict__ pts_t,  // (B,3,N)
                float* __restrict__ out,          // (B,3,NPOINT)
                unsigned long long* __restrict__ gkey,  // [B][NPOINT]
                unsigned* __restrict__ garr)            // [B][NPOINT]
{
#pragma clang fp contract(off)
    __shared__ unsigned long long s_key[2];   // double-buffered block key
    __shared__ int s_sel;

    const int blk = blockIdx.x;
    const int b = blk & (BATCH - 1);          // batch -> XCD (round-robin)
    const int k = blk >> 3;                   // sub-block within batch
    const int t = threadIdx.x;

    const float* __restrict__ px = pts_t + (size_t)b * 3 * N;
    const float* __restrict__ py = px + N;
    const float* __restrict__ pz = py + N;
    const f2* __restrict__ px2 = (const f2*)px;
    const f2* __restrict__ py2 = (const f2*)py;
    const f2* __restrict__ pz2 = (const f2*)pz;
    float* outx = out + (size_t)b * 3 * NPOINT;
    float* outy = outx + NPOINT;
    float* outz = outy + NPOINT;

    unsigned long long* __restrict__ mykey = gkey + (size_t)b * NPOINT;
    unsigned* __restrict__ myarr = garr + (size_t)b * NPOINT;

    // ---- all point state in registers: 8 f2 per array (16 pts/thread) ----
#define DECL(g) f2 x##g, y##g, z##g, T##g;
    REP8(DECL)
#undef DECL

#define LOADG(g) { const int q = k * QB + (g) * NT + t;           \
                   x##g = px2[q]; y##g = py2[q]; z##g = pz2[q];   \
                   T##g = (f2){1e10f, 1e10f}; }
    REP8(LOADG)
#undef LOADG

    if (t == 0) { s_key[0] = 0ull; s_key[1] = 0ull; }

    // First selected index is 0 (reference: idx[0] = 0).
    float lx = px[0], ly = py[0], lz = pz[0];
    if (k == 0 && t == 0) { outx[0] = lx; outy[0] = ly; outz[0] = lz; }
    __syncthreads();

    for (int j = 1; j < NPOINT; ++j) {
        const f2 lx2 = (f2){lx, lx};
        const f2 ly2 = (f2){ly, ly};
        const f2 lz2 = (f2){lz, lz};

        // --- update temps vs pivot; running per-lane max (pure VALU) ---
        f2 mx = (f2){0.0f, 0.0f};
#define UPD(g) { f2 dz = z##g - lz2;                                     \
                 f2 dx = x##g - lx2;                                     \
                 f2 dy = y##g - ly2;                                     \
                 f2 s  = (dx * dx + dy * dy) + dz * dz; /* numpy order */\
                 T##g.x = fminf(T##g.x, s.x);                            \
                 T##g.y = fminf(T##g.y, s.y);                            \
                 mx.x = fmaxf(mx.x, T##g.x);                             \
                 mx.y = fmaxf(mx.y, T##g.y); }
        REP8(UPD)
#undef UPD
        float vmax = fmaxf(mx.x, mx.y);

        // --- wave max (all lanes end with wave max) ---
#pragma unroll
        for (int off = 32; off >= 1; off >>= 1)
            vmax = fmaxf(vmax, __shfl_xor(vmax, off));

        // --- per-lane candidate (lowest original idx achieving vmax) ---
        int cand = N;
#define SCANG(g) { const int q = k * QB + (g) * NT + t;          \
                   cand = (T##g.y == vmax) ? 2 * q + 1 : cand;   \
                   cand = (T##g.x == vmax) ? 2 * q     : cand; }
        REP8R(SCANG)                        // descending -> lowest idx wins
#undef SCANG

        // --- block key: few lanes (usually 1) hold the wave max ---
        if (cand < N)
            atomicMax(&s_key[j & 1],
                      ((unsigned long long)__float_as_uint(vmax) << 32) |
                      (unsigned)(N - cand));
        __syncthreads();                    // barrier 1

        if (t == 0) {
            const unsigned long long bk = s_key[j & 1];
            s_key[(j + 1) & 1] = 0ull;      // prep other slot

            // publish block key, then arrive; all device-scope RMWs
            atomicMax(&mykey[j], bk);
            __threadfence();
            atomicAdd(&myarr[j], 1u);
            while (atomicAdd(&myarr[j], 0u) < KSPLIT)   // coherent RMW poll
                __builtin_amdgcn_s_sleep(1);
            __threadfence();
            const unsigned long long K = atomicAdd(&mykey[j], 0ull);
            s_sel = N - (int)(unsigned)(K & 0xffffffffu);
        }
        __syncthreads();                    // barrier 2

        const int sel = __builtin_amdgcn_readfirstlane(s_sel);
        lx = px[sel];                       // uniform -> scalar load (L2-hit)
        ly = py[sel];
        lz = pz[sel];
        if (k == 0 && t == 0) { outx[j] = lx; outy[j] = ly; outz[j] = lz; }
    }
}

extern "C" void kernel_launch(void* const* d_in, const int* in_sizes, int n_in,
                              void* d_out, int out_size, void* d_ws, size_t ws_size,
                              hipStream_t stream) {
    // d_in[0]: points_xyz (B,N,3) — unused
    // d_in[1]: points_xyz_t (B,3,N)
    // d_in[2]: features_with_xyz (B,67,N) — unused
    // d_ws: gkey u64[B][NPOINT] then garr u32[B][NPOINT] (192 KiB), zeroed
    const float* pts_t = (const float*)d_in[1];
    float* out = (float*)d_out;
    unsigned long long* gkey = (unsigned long long*)d_ws;
    unsigned* garr = (unsigned*)((char*)d_ws +
                     (size_t)BATCH * NPOINT * sizeof(unsigned long long));
    hipMemsetAsync(d_ws, 0,
                   (size_t)BATCH * NPOINT * (sizeof(unsigned long long) +
                                             sizeof(unsigned)), stream);
    fps_kernel<<<NBLK, NT, 0, stream>>>(pts_t, out, gkey, garr);
}